// Round 2
// baseline (665.689 us; speedup 1.0000x reference)
//
#include <hip/hip_runtime.h>

constexpr int HEADS = 4;

__device__ __forceinline__ float lrelu(float x) { return x > 0.f ? x : 0.2f * x; }

// ---------------- CSR build (edges grouped by dst; reused by all 3 layers) ----------------

__global__ void count_deg_kernel(const int* __restrict__ ei, int* __restrict__ deg,
                                 int E, int N) {
  int e = blockIdx.x * 256 + threadIdx.x;
  int EP = E + N;
  if (e < EP) {
    int d = (e < E) ? ei[E + e] : (e - E);   // self-loop tail
    atomicAdd(&deg[d], 1);
  }
}

__global__ void scan_block_kernel(const int* __restrict__ deg, int* __restrict__ rowp,
                                  int* __restrict__ partials, int N) {
  __shared__ int sm[1024];
  int t = threadIdx.x;
  int i = blockIdx.x * 1024 + t;
  int v = (i < N) ? deg[i] : 0;
  sm[t] = v;
  __syncthreads();
  for (int off = 1; off < 1024; off <<= 1) {
    int tmp = (t >= off) ? sm[t - off] : 0;
    __syncthreads();
    sm[t] += tmp;
    __syncthreads();
  }
  if (i < N) rowp[i] = sm[t] - v;            // exclusive within block
  if (t == 1023) partials[blockIdx.x] = sm[t];
}

__global__ void scan_partials_kernel(int* partials, int nb) {
  if (threadIdx.x == 0 && blockIdx.x == 0) {
    int acc = 0;
    for (int i = 0; i < nb && i < 1024; ++i) {
      int v = partials[i]; partials[i] = acc; acc += v;
    }
  }
}

__global__ void add_off_kernel(int* __restrict__ rowp, const int* __restrict__ partials,
                               int N, int EP) {
  int i = blockIdx.x * 256 + threadIdx.x;
  if (i < N) rowp[i] += partials[i >> 10];
  if (i == 0) rowp[N] = EP;
}

__global__ void scatter_kernel(const int* __restrict__ ei, const int* __restrict__ rowp,
                               int* __restrict__ cursor, int* __restrict__ col,
                               int E, int N) {
  int e = blockIdx.x * 256 + threadIdx.x;
  int EP = E + N;
  if (e < EP) {
    int s, d;
    if (e < E) { s = ei[e]; d = ei[E + e]; }
    else       { s = e - E; d = e - E; }
    int pos = rowp[d] + atomicAdd(&cursor[d], 1);
    col[pos] = s;
  }
}

// ---------------- GEMM: [N,128] @ [128,Fout], W tile staged in LDS ----------------
// block = 256 thr; tile 32 rows x 128 cols; 4x4 micro-tile.
// LDS: W 64KB + X 16KB = 80KB -> 2 blocks/CU.

__global__ __launch_bounds__(256, 2) void gemm_k128_kernel(
    const float* __restrict__ X, const float* __restrict__ W,
    float* __restrict__ Hout, int N, int Fout) {
  __shared__ float Wl[128 * 128];
  __shared__ float Xs[32 * 128];
  const int t = threadIdx.x;
  const int row0 = blockIdx.x * 32;
  const int colbase = blockIdx.y * 128;

#pragma unroll
  for (int i = 0; i < 16; ++i) {
    int idx = i * 256 + t;                 // float4 slot 0..4095
    int k = idx >> 5, m4 = idx & 31;
    *(float4*)&Wl[k * 128 + m4 * 4] =
        *(const float4*)&W[k * Fout + colbase + m4 * 4];
  }
#pragma unroll
  for (int i = 0; i < 4; ++i) {
    int idx = i * 256 + t;                 // float4 slot 0..1023
    int r = idx >> 5, k4 = idx & 31;
    int row = row0 + r;
    float4 v = make_float4(0.f, 0.f, 0.f, 0.f);
    if (row < N) v = *(const float4*)&X[row * 128 + k4 * 4];
    *(float4*)&Xs[r * 128 + k4 * 4] = v;
  }
  __syncthreads();

  const int tx = t & 31, ty = t >> 5;
  float acc[4][4] = {};
#pragma unroll 4
  for (int k = 0; k < 128; ++k) {
    float4 wv = *(const float4*)&Wl[k * 128 + tx * 4];
    float x0 = Xs[(ty * 4 + 0) * 128 + k];
    float x1 = Xs[(ty * 4 + 1) * 128 + k];
    float x2 = Xs[(ty * 4 + 2) * 128 + k];
    float x3 = Xs[(ty * 4 + 3) * 128 + k];
    acc[0][0] += x0 * wv.x; acc[0][1] += x0 * wv.y; acc[0][2] += x0 * wv.z; acc[0][3] += x0 * wv.w;
    acc[1][0] += x1 * wv.x; acc[1][1] += x1 * wv.y; acc[1][2] += x1 * wv.z; acc[1][3] += x1 * wv.w;
    acc[2][0] += x2 * wv.x; acc[2][1] += x2 * wv.y; acc[2][2] += x2 * wv.z; acc[2][3] += x2 * wv.w;
    acc[3][0] += x3 * wv.x; acc[3][1] += x3 * wv.y; acc[3][2] += x3 * wv.z; acc[3][3] += x3 * wv.w;
  }
#pragma unroll
  for (int j = 0; j < 4; ++j) {
    int row = row0 + ty * 4 + j;
    if (row < N) {
      float4 o = make_float4(acc[j][0], acc[j][1], acc[j][2], acc[j][3]);
      *(float4*)&Hout[row * Fout + colbase + tx * 4] = o;
    }
  }
}

// ---------------- per-node attention logits: one wave per (node, head) ----------------

__global__ __launch_bounds__(256) void alpha_kernel(
    const float* __restrict__ H, const float* __restrict__ a_s,
    const float* __restrict__ a_d, float* __restrict__ asrc,
    float* __restrict__ adst, int N, int C) {
  int n = blockIdx.x;
  int h = threadIdx.x >> 6;        // 4 waves = 4 heads
  int lane = threadIdx.x & 63;
  int F = HEADS * C;
  float ps = 0.f, pd = 0.f;
  if (lane < C) {
    float hv = H[n * F + h * C + lane];
    ps = hv * a_s[h * C + lane];
    pd = hv * a_d[h * C + lane];
  }
#pragma unroll
  for (int off = 32; off > 0; off >>= 1) {
    ps += __shfl_down(ps, off, 64);
    pd += __shfl_down(pd, off, 64);
  }
  if (lane == 0) { asrc[n * HEADS + h] = ps; adst[n * HEADS + h] = pd; }
}

// ---------------- atomic-free aggregation, fused segment-softmax ----------------
// exp(e)/sum(exp(e)) == exp(e-emax)/sum(exp(e-emax)); |e| is O(1) here -> skip segment max.

__global__ __launch_bounds__(128) void aggregate_concat_kernel(
    const float* __restrict__ H, const float* __restrict__ asrc,
    const float* __restrict__ adst, const float* __restrict__ bias,
    const int* __restrict__ rowp, const int* __restrict__ col,
    float* __restrict__ out, int N) {
  int n = blockIdx.x;
  int t = threadIdx.x;             // t = h*32 + c
  int h = t >> 5;
  float ad = adst[n * HEADS + h];
  int j = rowp[n], end = rowp[n + 1];
  float acc = 0.f, denom = 0.f;
  for (; j + 1 < end; j += 2) {
    int s0 = col[j], s1 = col[j + 1];
    float w0 = __expf(lrelu(asrc[s0 * HEADS + h] + ad));
    float w1 = __expf(lrelu(asrc[s1 * HEADS + h] + ad));
    float h0 = H[s0 * 128 + t];
    float h1 = H[s1 * 128 + t];
    denom += w0 + w1;
    acc += w0 * h0 + w1 * h1;
  }
  if (j < end) {
    int s0 = col[j];
    float w0 = __expf(lrelu(asrc[s0 * HEADS + h] + ad));
    denom += w0;
    acc += w0 * H[s0 * 128 + t];
  }
  out[n * 128 + t] = acc / denom + bias[t];
}

__global__ __launch_bounds__(256) void aggregate_mean_kernel(
    const float* __restrict__ H, const float* __restrict__ asrc,
    const float* __restrict__ adst, const float* __restrict__ bias,
    const int* __restrict__ rowp, const int* __restrict__ col,
    float* __restrict__ out, int N) {
  __shared__ float red[256];
  int n = blockIdx.x;
  int t = threadIdx.x;             // t = h*64 + c
  int h = t >> 6;
  float ad = adst[n * HEADS + h];
  int j = rowp[n], end = rowp[n + 1];
  float acc = 0.f, denom = 0.f;
  for (; j + 1 < end; j += 2) {
    int s0 = col[j], s1 = col[j + 1];
    float w0 = __expf(lrelu(asrc[s0 * HEADS + h] + ad));
    float w1 = __expf(lrelu(asrc[s1 * HEADS + h] + ad));
    float h0 = H[s0 * 256 + t];
    float h1 = H[s1 * 256 + t];
    denom += w0 + w1;
    acc += w0 * h0 + w1 * h1;
  }
  if (j < end) {
    int s0 = col[j];
    float w0 = __expf(lrelu(asrc[s0 * HEADS + h] + ad));
    denom += w0;
    acc += w0 * H[s0 * 256 + t];
  }
  red[t] = acc / denom;
  __syncthreads();
  if (t < 64)
    out[n * 64 + t] =
        0.25f * (red[t] + red[t + 64] + red[t + 128] + red[t + 192]) + bias[t];
}

// ---------------- host launch ----------------

extern "C" void kernel_launch(void* const* d_in, const int* in_sizes, int n_in,
                              void* d_out, int out_size, void* d_ws, size_t ws_size,
                              hipStream_t stream) {
  const float* x   = (const float*)d_in[0];
  const int*   ei  = (const int*)d_in[1];
  const float* W1  = (const float*)d_in[2];
  const float* as1 = (const float*)d_in[3];
  const float* ad1 = (const float*)d_in[4];
  const float* b1  = (const float*)d_in[5];
  const float* W2  = (const float*)d_in[6];
  const float* as2 = (const float*)d_in[7];
  const float* ad2 = (const float*)d_in[8];
  const float* b2  = (const float*)d_in[9];
  const float* W3  = (const float*)d_in[10];
  const float* as3 = (const float*)d_in[11];
  const float* ad3 = (const float*)d_in[12];
  const float* b3  = (const float*)d_in[13];
  float* out = (float*)d_out;

  const int N  = in_sizes[0] / 128;
  const int E  = in_sizes[1] / 2;
  const int EP = E + N;

  char* p = (char*)d_ws;
  auto carve = [&](size_t bytes) -> void* {
    void* r = (void*)p;
    p += (bytes + 255) & ~size_t(255);
    return r;
  };
  int*   deg  = (int*)carve(size_t(N) * 4);
  int*   rowp = (int*)carve(size_t(N + 1) * 4);
  int*   cur  = (int*)carve(size_t(N) * 4);
  int*   part = (int*)carve(1024 * 4);
  int*   col  = (int*)carve(size_t(EP) * 4);
  float* asrc = (float*)carve(size_t(N) * HEADS * 4);
  float* adst = (float*)carve(size_t(N) * HEADS * 4);
  float* hb1  = (float*)carve(size_t(N) * 128 * 4);
  float* hb2  = (float*)carve(size_t(N) * 128 * 4);
  float* hb3  = (float*)carve(size_t(N) * 256 * 4);

  hipMemsetAsync(deg, 0, size_t(N) * 4, stream);
  hipMemsetAsync(cur, 0, size_t(N) * 4, stream);

  int gEP = (EP + 255) / 256;
  count_deg_kernel<<<gEP, 256, 0, stream>>>(ei, deg, E, N);
  int nb = (N + 1023) / 1024;
  scan_block_kernel<<<nb, 1024, 0, stream>>>(deg, rowp, part, N);
  scan_partials_kernel<<<1, 64, 0, stream>>>(part, nb);
  add_off_kernel<<<(N + 256) / 256, 256, 0, stream>>>(rowp, part, N, EP);
  scatter_kernel<<<gEP, 256, 0, stream>>>(ei, rowp, cur, col, E, N);

  int gR = (N + 31) / 32;
  // layer 1: F_in=128 -> H=4,C=32 concat
  gemm_k128_kernel<<<dim3(gR, 1), 256, 0, stream>>>(x, W1, hb1, N, 128);
  alpha_kernel<<<N, 256, 0, stream>>>(hb1, as1, ad1, asrc, adst, N, 32);
  aggregate_concat_kernel<<<N, 128, 0, stream>>>(hb1, asrc, adst, b1, rowp, col, hb2, N);
  // layer 2
  gemm_k128_kernel<<<dim3(gR, 1), 256, 0, stream>>>(hb2, W2, hb1, N, 128);
  alpha_kernel<<<N, 256, 0, stream>>>(hb1, as2, ad2, asrc, adst, N, 32);
  aggregate_concat_kernel<<<N, 128, 0, stream>>>(hb1, asrc, adst, b2, rowp, col, hb2, N);
  // layer 3: H=4, OUT=64, mean over heads
  gemm_k128_kernel<<<dim3(gR, 2), 256, 0, stream>>>(hb2, W3, hb3, N, 256);
  alpha_kernel<<<N, 256, 0, stream>>>(hb3, as3, ad3, asrc, adst, N, 64);
  aggregate_mean_kernel<<<N, 256, 0, stream>>>(hb3, asrc, adst, b3, rowp, col, out, N);
}

// Round 3
// 572.117 us; speedup vs baseline: 1.1636x; 1.1636x over previous
//
#include <hip/hip_runtime.h>
#include <hip/hip_fp16.h>

constexpr int HEADS = 4;

__device__ __forceinline__ float lrelu(float x) { return x > 0.f ? x : 0.2f * x; }

// ---------------- CSR build (edges grouped by dst; reused by all 3 layers) ----------------

__global__ void count_deg_kernel(const int* __restrict__ ei, int* __restrict__ deg,
                                 int E, int N) {
  int e = blockIdx.x * 256 + threadIdx.x;
  int EP = E + N;
  if (e < EP) {
    int d = (e < E) ? ei[E + e] : (e - E);   // self-loop tail
    atomicAdd(&deg[d], 1);
  }
}

__global__ void scan_block_kernel(const int* __restrict__ deg, int* __restrict__ rowp,
                                  int* __restrict__ partials, int N) {
  __shared__ int sm[1024];
  int t = threadIdx.x;
  int i = blockIdx.x * 1024 + t;
  int v = (i < N) ? deg[i] : 0;
  sm[t] = v;
  __syncthreads();
  for (int off = 1; off < 1024; off <<= 1) {
    int tmp = (t >= off) ? sm[t - off] : 0;
    __syncthreads();
    sm[t] += tmp;
    __syncthreads();
  }
  if (i < N) rowp[i] = sm[t] - v;            // exclusive within block
  if (t == 1023) partials[blockIdx.x] = sm[t];
}

__global__ void scan_partials_kernel(int* partials, int nb) {
  if (threadIdx.x == 0 && blockIdx.x == 0) {
    int acc = 0;
    for (int i = 0; i < nb && i < 1024; ++i) {
      int v = partials[i]; partials[i] = acc; acc += v;
    }
  }
}

__global__ void add_off_kernel(int* __restrict__ rowp, const int* __restrict__ partials,
                               int N, int EP) {
  int i = blockIdx.x * 256 + threadIdx.x;
  if (i < N) rowp[i] += partials[i >> 10];
  if (i == 0) rowp[N] = EP;
}

__global__ void scatter_kernel(const int* __restrict__ ei, const int* __restrict__ rowp,
                               int* __restrict__ cursor, int* __restrict__ col,
                               int E, int N) {
  int e = blockIdx.x * 256 + threadIdx.x;
  int EP = E + N;
  if (e < EP) {
    int s, d;
    if (e < E) { s = ei[e]; d = ei[E + e]; }
    else       { s = e - E; d = e - E; }
    int pos = rowp[d] + atomicAdd(&cursor[d], 1);
    col[pos] = s;
  }
}

// ---------------- GEMM: [N,128]fp32 @ [128,Fout]fp32 -> Hout fp16 ----------------
// block = 256 thr; tile 32 rows x 128 cols; 4x4 micro-tile.
// LDS: W 64KB + X 16KB = 80KB -> 2 blocks/CU.

__global__ __launch_bounds__(256, 2) void gemm_k128_kernel(
    const float* __restrict__ X, const float* __restrict__ W,
    __half* __restrict__ Hout, int N, int Fout) {
  __shared__ float Wl[128 * 128];
  __shared__ float Xs[32 * 128];
  const int t = threadIdx.x;
  const int row0 = blockIdx.x * 32;
  const int colbase = blockIdx.y * 128;

#pragma unroll
  for (int i = 0; i < 16; ++i) {
    int idx = i * 256 + t;                 // float4 slot 0..4095
    int k = idx >> 5, m4 = idx & 31;
    *(float4*)&Wl[k * 128 + m4 * 4] =
        *(const float4*)&W[k * Fout + colbase + m4 * 4];
  }
#pragma unroll
  for (int i = 0; i < 4; ++i) {
    int idx = i * 256 + t;                 // float4 slot 0..1023
    int r = idx >> 5, k4 = idx & 31;
    int row = row0 + r;
    float4 v = make_float4(0.f, 0.f, 0.f, 0.f);
    if (row < N) v = *(const float4*)&X[row * 128 + k4 * 4];
    *(float4*)&Xs[r * 128 + k4 * 4] = v;
  }
  __syncthreads();

  const int tx = t & 31, ty = t >> 5;
  float acc[4][4] = {};
#pragma unroll 4
  for (int k = 0; k < 128; ++k) {
    float4 wv = *(const float4*)&Wl[k * 128 + tx * 4];
    float x0 = Xs[(ty * 4 + 0) * 128 + k];
    float x1 = Xs[(ty * 4 + 1) * 128 + k];
    float x2 = Xs[(ty * 4 + 2) * 128 + k];
    float x3 = Xs[(ty * 4 + 3) * 128 + k];
    acc[0][0] += x0 * wv.x; acc[0][1] += x0 * wv.y; acc[0][2] += x0 * wv.z; acc[0][3] += x0 * wv.w;
    acc[1][0] += x1 * wv.x; acc[1][1] += x1 * wv.y; acc[1][2] += x1 * wv.z; acc[1][3] += x1 * wv.w;
    acc[2][0] += x2 * wv.x; acc[2][1] += x2 * wv.y; acc[2][2] += x2 * wv.z; acc[2][3] += x2 * wv.w;
    acc[3][0] += x3 * wv.x; acc[3][1] += x3 * wv.y; acc[3][2] += x3 * wv.z; acc[3][3] += x3 * wv.w;
  }
#pragma unroll
  for (int j = 0; j < 4; ++j) {
    int row = row0 + ty * 4 + j;
    if (row < N) {
      __half hv[4];
      hv[0] = __float2half_rn(acc[j][0]);
      hv[1] = __float2half_rn(acc[j][1]);
      hv[2] = __float2half_rn(acc[j][2]);
      hv[3] = __float2half_rn(acc[j][3]);
      *(float2*)&Hout[row * Fout + colbase + tx * 4] = *(float2*)hv;
    }
  }
}

// ---------------- per-node attention logits: one wave per (node, head) ----------------

__global__ __launch_bounds__(256) void alpha_kernel(
    const __half* __restrict__ H, const float* __restrict__ a_s,
    const float* __restrict__ a_d, float* __restrict__ asrc,
    float* __restrict__ adst, int N, int C) {
  int n = blockIdx.x;
  int h = threadIdx.x >> 6;        // 4 waves = 4 heads
  int lane = threadIdx.x & 63;
  int F = HEADS * C;
  float ps = 0.f, pd = 0.f;
  if (lane < C) {
    float hv = __half2float(H[n * F + h * C + lane]);
    ps = hv * a_s[h * C + lane];
    pd = hv * a_d[h * C + lane];
  }
#pragma unroll
  for (int off = 32; off > 0; off >>= 1) {
    ps += __shfl_down(ps, off, 64);
    pd += __shfl_down(pd, off, 64);
  }
  if (lane == 0) { asrc[n * HEADS + h] = ps; adst[n * HEADS + h] = pd; }
}

// ---------------- atomic-free aggregation, fused segment-softmax ----------------
// exp(e)/sum == exp(e-emax)/sum(exp(e-emax)); |e| is O(1) here -> skip segment max.
// 4 waves per block = 4 nodes; each lane handles one half2 (2 channels).

__global__ __launch_bounds__(256) void aggregate_concat_kernel(
    const __half* __restrict__ H, const float* __restrict__ asrc,
    const float* __restrict__ adst, const float* __restrict__ bias,
    const int* __restrict__ rowp, const int* __restrict__ col,
    float* __restrict__ out, int N) {
  int n = blockIdx.x * 4 + (threadIdx.x >> 6);
  if (n >= N) return;
  int lane = threadIdx.x & 63;     // channels 2*lane, 2*lane+1
  int h = lane >> 4;               // 16 lanes per head (32 ch)
  float ad = adst[n * HEADS + h];
  int j = rowp[n], end = rowp[n + 1];
  float ax = 0.f, ay = 0.f, denom = 0.f;
  for (; j + 1 < end; j += 2) {
    int s0 = col[j], s1 = col[j + 1];
    float w0 = __expf(lrelu(asrc[s0 * HEADS + h] + ad));
    float w1 = __expf(lrelu(asrc[s1 * HEADS + h] + ad));
    float2 f0 = __half22float2(*(const __half2*)&H[s0 * 128 + lane * 2]);
    float2 f1 = __half22float2(*(const __half2*)&H[s1 * 128 + lane * 2]);
    denom += w0 + w1;
    ax += w0 * f0.x + w1 * f1.x;
    ay += w0 * f0.y + w1 * f1.y;
  }
  if (j < end) {
    int s0 = col[j];
    float w0 = __expf(lrelu(asrc[s0 * HEADS + h] + ad));
    float2 f0 = __half22float2(*(const __half2*)&H[s0 * 128 + lane * 2]);
    denom += w0;
    ax += w0 * f0.x;
    ay += w0 * f0.y;
  }
  float inv = 1.f / denom;
  float2 o = make_float2(ax * inv + bias[lane * 2], ay * inv + bias[lane * 2 + 1]);
  *(float2*)&out[n * 128 + lane * 2] = o;
}

// layer 3: H rows are 256 ch fp16; 128 thr/node, each half2; mean over 4 heads -> 64 ch.

__global__ __launch_bounds__(128) void aggregate_mean_kernel(
    const __half* __restrict__ H, const float* __restrict__ asrc,
    const float* __restrict__ adst, const float* __restrict__ bias,
    const int* __restrict__ rowp, const int* __restrict__ col,
    float* __restrict__ out, int N) {
  __shared__ float2 red[128];
  int n = blockIdx.x;
  int t = threadIdx.x;             // channels 2t, 2t+1
  int h = t >> 5;                  // 32 threads per head (64 ch)
  float ad = adst[n * HEADS + h];
  int j = rowp[n], end = rowp[n + 1];
  float ax = 0.f, ay = 0.f, denom = 0.f;
  for (; j + 1 < end; j += 2) {
    int s0 = col[j], s1 = col[j + 1];
    float w0 = __expf(lrelu(asrc[s0 * HEADS + h] + ad));
    float w1 = __expf(lrelu(asrc[s1 * HEADS + h] + ad));
    float2 f0 = __half22float2(*(const __half2*)&H[s0 * 256 + t * 2]);
    float2 f1 = __half22float2(*(const __half2*)&H[s1 * 256 + t * 2]);
    denom += w0 + w1;
    ax += w0 * f0.x + w1 * f1.x;
    ay += w0 * f0.y + w1 * f1.y;
  }
  if (j < end) {
    int s0 = col[j];
    float w0 = __expf(lrelu(asrc[s0 * HEADS + h] + ad));
    float2 f0 = __half22float2(*(const __half2*)&H[s0 * 256 + t * 2]);
    denom += w0;
    ax += w0 * f0.x;
    ay += w0 * f0.y;
  }
  float inv = 1.f / denom;
  red[t] = make_float2(ax * inv, ay * inv);
  __syncthreads();
  if (t < 32) {
    float2 r0 = red[t], r1 = red[t + 32], r2 = red[t + 64], r3 = red[t + 96];
    float2 o = make_float2(0.25f * (r0.x + r1.x + r2.x + r3.x) + bias[t * 2],
                           0.25f * (r0.y + r1.y + r2.y + r3.y) + bias[t * 2 + 1]);
    *(float2*)&out[n * 64 + t * 2] = o;
  }
}

// ---------------- host launch ----------------

extern "C" void kernel_launch(void* const* d_in, const int* in_sizes, int n_in,
                              void* d_out, int out_size, void* d_ws, size_t ws_size,
                              hipStream_t stream) {
  const float* x   = (const float*)d_in[0];
  const int*   ei  = (const int*)d_in[1];
  const float* W1  = (const float*)d_in[2];
  const float* as1 = (const float*)d_in[3];
  const float* ad1 = (const float*)d_in[4];
  const float* b1  = (const float*)d_in[5];
  const float* W2  = (const float*)d_in[6];
  const float* as2 = (const float*)d_in[7];
  const float* ad2 = (const float*)d_in[8];
  const float* b2  = (const float*)d_in[9];
  const float* W3  = (const float*)d_in[10];
  const float* as3 = (const float*)d_in[11];
  const float* ad3 = (const float*)d_in[12];
  const float* b3  = (const float*)d_in[13];
  float* out = (float*)d_out;

  const int N  = in_sizes[0] / 128;
  const int E  = in_sizes[1] / 2;
  const int EP = E + N;

  char* p = (char*)d_ws;
  auto carve = [&](size_t bytes) -> void* {
    void* r = (void*)p;
    p += (bytes + 255) & ~size_t(255);
    return r;
  };
  int*    deg  = (int*)carve(size_t(N) * 4);
  int*    rowp = (int*)carve(size_t(N + 1) * 4);
  int*    cur  = (int*)carve(size_t(N) * 4);
  int*    part = (int*)carve(1024 * 4);
  int*    col  = (int*)carve(size_t(EP) * 4);
  float*  asrc = (float*)carve(size_t(N) * HEADS * 4);
  float*  adst = (float*)carve(size_t(N) * HEADS * 4);
  __half* h16a = (__half*)carve(size_t(N) * 128 * 2);   // layer1/2 H (fp16)
  __half* h16b = (__half*)carve(size_t(N) * 256 * 2);   // layer3 H (fp16)
  float*  f32a = (float*)carve(size_t(N) * 128 * 4);    // aggregation outputs (fp32)

  hipMemsetAsync(deg, 0, size_t(N) * 4, stream);
  hipMemsetAsync(cur, 0, size_t(N) * 4, stream);

  int gEP = (EP + 255) / 256;
  count_deg_kernel<<<gEP, 256, 0, stream>>>(ei, deg, E, N);
  int nb = (N + 1023) / 1024;
  scan_block_kernel<<<nb, 1024, 0, stream>>>(deg, rowp, part, N);
  scan_partials_kernel<<<1, 64, 0, stream>>>(part, nb);
  add_off_kernel<<<(N + 256) / 256, 256, 0, stream>>>(rowp, part, N, EP);
  scatter_kernel<<<gEP, 256, 0, stream>>>(ei, rowp, cur, col, E, N);

  int gR = (N + 31) / 32;
  int gN4 = (N + 3) / 4;
  // layer 1: F_in=128 -> H=4,C=32 concat
  gemm_k128_kernel<<<dim3(gR, 1), 256, 0, stream>>>(x, W1, h16a, N, 128);
  alpha_kernel<<<N, 256, 0, stream>>>(h16a, as1, ad1, asrc, adst, N, 32);
  aggregate_concat_kernel<<<gN4, 256, 0, stream>>>(h16a, asrc, adst, b1, rowp, col, f32a, N);
  // layer 2
  gemm_k128_kernel<<<dim3(gR, 1), 256, 0, stream>>>(f32a, W2, h16a, N, 128);
  alpha_kernel<<<N, 256, 0, stream>>>(h16a, as2, ad2, asrc, adst, N, 32);
  aggregate_concat_kernel<<<gN4, 256, 0, stream>>>(h16a, asrc, adst, b2, rowp, col, f32a, N);
  // layer 3: H=4, OUT=64, mean over heads
  gemm_k128_kernel<<<dim3(gR, 2), 256, 0, stream>>>(f32a, W3, h16b, N, 256);
  alpha_kernel<<<N, 256, 0, stream>>>(h16b, as3, ad3, asrc, adst, N, 64);
  aggregate_mean_kernel<<<N, 128, 0, stream>>>(h16b, asrc, adst, b3, rowp, col, out, N);
}

// Round 4
// 560.599 us; speedup vs baseline: 1.1875x; 1.0205x over previous
//
#include <hip/hip_runtime.h>
#include <hip/hip_fp16.h>

constexpr int HEADS = 4;

typedef _Float16 half8 __attribute__((ext_vector_type(8)));
typedef _Float16 half2v __attribute__((ext_vector_type(2)));
typedef float f32x4 __attribute__((ext_vector_type(4)));

__device__ __forceinline__ float lrelu(float x) { return x > 0.f ? x : 0.2f * x; }

// ---------------- CSR build (edges grouped by dst; reused by all 3 layers) ----------------

__global__ void count_deg_kernel(const int* __restrict__ ei, int* __restrict__ deg,
                                 int E, int N) {
  int e = blockIdx.x * 256 + threadIdx.x;
  int EP = E + N;
  if (e < EP) {
    int d = (e < E) ? ei[E + e] : (e - E);   // self-loop tail
    atomicAdd(&deg[d], 1);
  }
}

__global__ void scan_block_kernel(const int* __restrict__ deg, int* __restrict__ rowp,
                                  int* __restrict__ partials, int N) {
  __shared__ int sm[1024];
  int t = threadIdx.x;
  int i = blockIdx.x * 1024 + t;
  int v = (i < N) ? deg[i] : 0;
  sm[t] = v;
  __syncthreads();
  for (int off = 1; off < 1024; off <<= 1) {
    int tmp = (t >= off) ? sm[t - off] : 0;
    __syncthreads();
    sm[t] += tmp;
    __syncthreads();
  }
  if (i < N) rowp[i] = sm[t] - v;            // exclusive within block
  if (t == 1023) partials[blockIdx.x] = sm[t];
}

__global__ void scan_partials_kernel(int* partials, int nb) {
  if (threadIdx.x == 0 && blockIdx.x == 0) {
    int acc = 0;
    for (int i = 0; i < nb && i < 1024; ++i) {
      int v = partials[i]; partials[i] = acc; acc += v;
    }
  }
}

__global__ void add_off_kernel(int* __restrict__ rowp, const int* __restrict__ partials,
                               int N, int EP) {
  int i = blockIdx.x * 256 + threadIdx.x;
  if (i < N) rowp[i] += partials[i >> 10];
  if (i == 0) rowp[N] = EP;
}

__global__ void scatter_kernel(const int* __restrict__ ei, const int* __restrict__ rowp,
                               int* __restrict__ cursor, int* __restrict__ col,
                               int* __restrict__ dstarr, int E, int N) {
  int e = blockIdx.x * 256 + threadIdx.x;
  int EP = E + N;
  if (e < EP) {
    int s, d;
    if (e < E) { s = ei[e]; d = ei[E + e]; }
    else       { s = e - E; d = e - E; }
    int pos = rowp[d] + atomicAdd(&cursor[d], 1);
    col[pos] = s;
    dstarr[pos] = d;
  }
}

// ---------------- fp32 -> fp16 conversions ----------------

__global__ void convert_x_kernel(const float* __restrict__ X, _Float16* __restrict__ Xh,
                                 int total8) {       // total elements / 8
  int i = blockIdx.x * 256 + threadIdx.x;
  if (i < total8) {
    float4 a = *(const float4*)&X[i * 8];
    float4 b = *(const float4*)&X[i * 8 + 4];
    half8 o = { (_Float16)a.x, (_Float16)a.y, (_Float16)a.z, (_Float16)a.w,
                (_Float16)b.x, (_Float16)b.y, (_Float16)b.z, (_Float16)b.w };
    *(half8*)&Xh[i * 8] = o;
  }
}

// W [128, Fout] fp32 -> Wt [Fout, 128] fp16 (transposed)
__global__ void convert_wt_kernel(const float* __restrict__ W, _Float16* __restrict__ Wt,
                                  int Fout) {
  int i = blockIdx.x * 256 + threadIdx.x;   // i over 128*Fout
  if (i < 128 * Fout) {
    int c = i >> 7, k = i & 127;
    Wt[c * 128 + k] = (_Float16)W[k * Fout + c];
  }
}

// ---------------- MFMA GEMM: Xh [N,128] f16 @ Wt [Fout,128] f16 -> O [N,Fout] f16 ----
// 4 waves/block; wave w owns rows [blk*64 + w*16, +16), cols = 128-col panel (blockIdx.y).
// A-frag: row=lane&15, k=(lane>>4)*8+j.  B-frag: col=lane&15 (Wt row), same k.
// C/D: col=lane&15, row=(lane>>4)*4+reg.

__global__ __launch_bounds__(256) void gemm_mfma_kernel(
    const _Float16* __restrict__ X, const _Float16* __restrict__ Wt,
    _Float16* __restrict__ O, int N, int Fout) {
  const int w = threadIdx.x >> 6;
  const int lane = threadIdx.x & 63;
  const int r = lane & 15, g = lane >> 4;
  const int row0 = blockIdx.x * 64 + w * 16;
  const int colpan = blockIdx.y * 128;

  int rowl = row0 + r;
  if (rowl >= N) rowl = N - 1;                     // clamp for loads; store guarded

  f32x4 acc[8];
#pragma unroll
  for (int c = 0; c < 8; ++c) acc[c] = {0.f, 0.f, 0.f, 0.f};

#pragma unroll
  for (int s = 0; s < 4; ++s) {
    half8 a = *(const half8*)&X[(size_t)rowl * 128 + s * 32 + g * 8];
#pragma unroll
    for (int c = 0; c < 8; ++c) {
      half8 b = *(const half8*)&Wt[(size_t)(colpan + c * 16 + r) * 128 + s * 32 + g * 8];
      acc[c] = __builtin_amdgcn_mfma_f32_16x16x32_f16(a, b, acc[c], 0, 0, 0);
    }
  }

#pragma unroll
  for (int c = 0; c < 8; ++c) {
    int ocol = colpan + c * 16 + r;
#pragma unroll
    for (int q = 0; q < 4; ++q) {
      int orow = row0 + g * 4 + q;
      if (orow < N) O[(size_t)orow * Fout + ocol] = (_Float16)acc[c][q];
    }
  }
}

// ---------------- per-node attention logits: one wave per (node, head) ----------------

__global__ __launch_bounds__(256) void alpha_kernel(
    const _Float16* __restrict__ H, const float* __restrict__ a_s,
    const float* __restrict__ a_d, float* __restrict__ asrc,
    float* __restrict__ adst, int N, int C) {
  int n = blockIdx.x;
  int h = threadIdx.x >> 6;        // 4 waves = 4 heads
  int lane = threadIdx.x & 63;
  int F = HEADS * C;
  float ps = 0.f, pd = 0.f;
  if (lane < C) {
    float hv = (float)H[n * F + h * C + lane];
    ps = hv * a_s[h * C + lane];
    pd = hv * a_d[h * C + lane];
  }
#pragma unroll
  for (int off = 32; off > 0; off >>= 1) {
    ps += __shfl_down(ps, off, 64);
    pd += __shfl_down(pd, off, 64);
  }
  if (lane == 0) { asrc[n * HEADS + h] = ps; adst[n * HEADS + h] = pd; }
}

// ---------------- per-edge softmax weights (computed ONCE per (edge,head)) ----------------

__global__ __launch_bounds__(256) void ew_kernel(
    const int* __restrict__ col, const int* __restrict__ dstarr,
    const float* __restrict__ asrc, const float* __restrict__ adst,
    float* __restrict__ wgt, int EP) {
  int j = blockIdx.x * 256 + threadIdx.x;
  if (j < EP) {
    int s = col[j], d = dstarr[j];
    float4 a = *(const float4*)&asrc[s * 4];
    float4 b = *(const float4*)&adst[d * 4];
    float4 o;
    o.x = __expf(lrelu(a.x + b.x));
    o.y = __expf(lrelu(a.y + b.y));
    o.z = __expf(lrelu(a.z + b.z));
    o.w = __expf(lrelu(a.w + b.w));
    *(float4*)&wgt[j * 4] = o;
  }
}

// ---------------- atomic-free aggregation (weights preloaded) ----------------
// 4 waves per block = 4 nodes; each lane handles one half2 (2 channels of 128).

__global__ __launch_bounds__(256) void aggregate_concat_kernel(
    const _Float16* __restrict__ H, const float* __restrict__ wgt,
    const float* __restrict__ bias, const int* __restrict__ rowp,
    const int* __restrict__ col, _Float16* __restrict__ out, int N) {
  int n = blockIdx.x * 4 + (threadIdx.x >> 6);
  if (n >= N) return;
  int lane = threadIdx.x & 63;     // channels 2*lane, 2*lane+1
  int h = lane >> 4;               // 16 lanes per head (32 ch)
  int j = rowp[n], end = rowp[n + 1];
  float ax = 0.f, ay = 0.f, denom = 0.f;
  for (; j + 1 < end; j += 2) {
    int s0 = col[j], s1 = col[j + 1];
    float w0 = wgt[j * 4 + h];
    float w1 = wgt[j * 4 + 4 + h];
    half2v f0 = *(const half2v*)&H[s0 * 128 + lane * 2];
    half2v f1 = *(const half2v*)&H[s1 * 128 + lane * 2];
    denom += w0 + w1;
    ax += w0 * (float)f0.x + w1 * (float)f1.x;
    ay += w0 * (float)f0.y + w1 * (float)f1.y;
  }
  if (j < end) {
    int s0 = col[j];
    float w0 = wgt[j * 4 + h];
    half2v f0 = *(const half2v*)&H[s0 * 128 + lane * 2];
    denom += w0;
    ax += w0 * (float)f0.x;
    ay += w0 * (float)f0.y;
  }
  float inv = 1.f / denom;
  half2v o;
  o.x = (_Float16)(ax * inv + bias[lane * 2]);
  o.y = (_Float16)(ay * inv + bias[lane * 2 + 1]);
  *(half2v*)&out[n * 128 + lane * 2] = o;
}

// layer 3: H rows 256 ch fp16; 128 thr/node; mean over 4 heads -> 64 ch fp32 out.

__global__ __launch_bounds__(128) void aggregate_mean_kernel(
    const _Float16* __restrict__ H, const float* __restrict__ wgt,
    const float* __restrict__ bias, const int* __restrict__ rowp,
    const int* __restrict__ col, float* __restrict__ out, int N) {
  __shared__ float2 red[128];
  int n = blockIdx.x;
  int t = threadIdx.x;             // channels 2t, 2t+1
  int h = t >> 5;                  // 32 threads per head (64 ch)
  int j = rowp[n], end = rowp[n + 1];
  float ax = 0.f, ay = 0.f, denom = 0.f;
  for (; j + 1 < end; j += 2) {
    int s0 = col[j], s1 = col[j + 1];
    float w0 = wgt[j * 4 + h];
    float w1 = wgt[j * 4 + 4 + h];
    half2v f0 = *(const half2v*)&H[s0 * 256 + t * 2];
    half2v f1 = *(const half2v*)&H[s1 * 256 + t * 2];
    denom += w0 + w1;
    ax += w0 * (float)f0.x + w1 * (float)f1.x;
    ay += w0 * (float)f0.y + w1 * (float)f1.y;
  }
  if (j < end) {
    int s0 = col[j];
    float w0 = wgt[j * 4 + h];
    half2v f0 = *(const half2v*)&H[s0 * 256 + t * 2];
    denom += w0;
    ax += w0 * (float)f0.x;
    ay += w0 * (float)f0.y;
  }
  float inv = 1.f / denom;
  red[t] = make_float2(ax * inv, ay * inv);
  __syncthreads();
  if (t < 32) {
    float2 r0 = red[t], r1 = red[t + 32], r2 = red[t + 64], r3 = red[t + 96];
    float2 o = make_float2(0.25f * (r0.x + r1.x + r2.x + r3.x) + bias[t * 2],
                           0.25f * (r0.y + r1.y + r2.y + r3.y) + bias[t * 2 + 1]);
    *(float2*)&out[n * 64 + t * 2] = o;
  }
}

// ---------------- host launch ----------------

extern "C" void kernel_launch(void* const* d_in, const int* in_sizes, int n_in,
                              void* d_out, int out_size, void* d_ws, size_t ws_size,
                              hipStream_t stream) {
  const float* x   = (const float*)d_in[0];
  const int*   ei  = (const int*)d_in[1];
  const float* W1  = (const float*)d_in[2];
  const float* as1 = (const float*)d_in[3];
  const float* ad1 = (const float*)d_in[4];
  const float* b1  = (const float*)d_in[5];
  const float* W2  = (const float*)d_in[6];
  const float* as2 = (const float*)d_in[7];
  const float* ad2 = (const float*)d_in[8];
  const float* b2  = (const float*)d_in[9];
  const float* W3  = (const float*)d_in[10];
  const float* as3 = (const float*)d_in[11];
  const float* ad3 = (const float*)d_in[12];
  const float* b3  = (const float*)d_in[13];
  float* out = (float*)d_out;

  const int N  = in_sizes[0] / 128;
  const int E  = in_sizes[1] / 2;
  const int EP = E + N;

  char* p = (char*)d_ws;
  auto carve = [&](size_t bytes) -> void* {
    void* r = (void*)p;
    p += (bytes + 255) & ~size_t(255);
    return r;
  };
  int*      deg  = (int*)carve(size_t(N) * 4);
  int*      rowp = (int*)carve(size_t(N + 1) * 4);
  int*      cur  = (int*)carve(size_t(N) * 4);
  int*      part = (int*)carve(1024 * 4);
  int*      col  = (int*)carve(size_t(EP) * 4);
  int*      darr = (int*)carve(size_t(EP) * 4);
  float*    asrc = (float*)carve(size_t(N) * HEADS * 4);
  float*    adst = (float*)carve(size_t(N) * HEADS * 4);
  float*    wgt  = (float*)carve(size_t(EP) * HEADS * 4);
  _Float16* Xh   = (_Float16*)carve(size_t(N) * 128 * 2);
  _Float16* Wt1  = (_Float16*)carve(128 * 128 * 2);
  _Float16* Wt2  = (_Float16*)carve(128 * 128 * 2);
  _Float16* Wt3  = (_Float16*)carve(256 * 128 * 2);
  _Float16* Hb   = (_Float16*)carve(size_t(N) * 256 * 2);  // gemm outputs (128 or 256 wide)
  _Float16* Ab   = (_Float16*)carve(size_t(N) * 128 * 2);  // aggregation outputs

  hipMemsetAsync(deg, 0, size_t(N) * 4, stream);
  hipMemsetAsync(cur, 0, size_t(N) * 4, stream);

  int gEP = (EP + 255) / 256;
  count_deg_kernel<<<gEP, 256, 0, stream>>>(ei, deg, E, N);
  int nb = (N + 1023) / 1024;
  scan_block_kernel<<<nb, 1024, 0, stream>>>(deg, rowp, part, N);
  scan_partials_kernel<<<1, 64, 0, stream>>>(part, nb);
  add_off_kernel<<<(N + 256) / 256, 256, 0, stream>>>(rowp, part, N, EP);
  scatter_kernel<<<gEP, 256, 0, stream>>>(ei, rowp, cur, col, darr, E, N);

  convert_x_kernel<<<(N * 128 / 8 + 255) / 256, 256, 0, stream>>>(x, Xh, N * 128 / 8);
  convert_wt_kernel<<<(128 * 128 + 255) / 256, 256, 0, stream>>>(W1, Wt1, 128);
  convert_wt_kernel<<<(128 * 128 + 255) / 256, 256, 0, stream>>>(W2, Wt2, 128);
  convert_wt_kernel<<<(128 * 256 + 255) / 256, 256, 0, stream>>>(W3, Wt3, 256);

  int gM = (N + 63) / 64;
  int gN4 = (N + 3) / 4;

  // layer 1
  gemm_mfma_kernel<<<dim3(gM, 1), 256, 0, stream>>>(Xh, Wt1, Hb, N, 128);
  alpha_kernel<<<N, 256, 0, stream>>>(Hb, as1, ad1, asrc, adst, N, 32);
  ew_kernel<<<gEP, 256, 0, stream>>>(col, darr, asrc, adst, wgt, EP);
  aggregate_concat_kernel<<<gN4, 256, 0, stream>>>(Hb, wgt, b1, rowp, col, Ab, N);
  // layer 2
  gemm_mfma_kernel<<<dim3(gM, 1), 256, 0, stream>>>(Ab, Wt2, Hb, N, 128);
  alpha_kernel<<<N, 256, 0, stream>>>(Hb, as2, ad2, asrc, adst, N, 32);
  ew_kernel<<<gEP, 256, 0, stream>>>(col, darr, asrc, adst, wgt, EP);
  aggregate_concat_kernel<<<gN4, 256, 0, stream>>>(Hb, wgt, b2, rowp, col, Ab, N);
  // layer 3 (Fout=256, mean over heads)
  gemm_mfma_kernel<<<dim3(gM, 2), 256, 0, stream>>>(Ab, Wt3, Hb, N, 256);
  alpha_kernel<<<N, 256, 0, stream>>>(Hb, as3, ad3, asrc, adst, N, 64);
  ew_kernel<<<gEP, 256, 0, stream>>>(col, darr, asrc, adst, wgt, EP);
  aggregate_mean_kernel<<<N, 128, 0, stream>>>(Hb, wgt, b3, rowp, col, out, N);
}

// Round 5
// 450.100 us; speedup vs baseline: 1.4790x; 1.2455x over previous
//
#include <hip/hip_runtime.h>
#include <hip/hip_fp16.h>

constexpr int HEADS = 4;

typedef _Float16 half8 __attribute__((ext_vector_type(8)));
typedef _Float16 half2v __attribute__((ext_vector_type(2)));
typedef float f32x4 __attribute__((ext_vector_type(4)));

__device__ __forceinline__ float lrelu(float x) { return x > 0.f ? x : 0.2f * x; }

// ---------------- CSR build (edges grouped by dst; reused by all 3 layers) ----------------

__global__ void count_deg_kernel(const int* __restrict__ ei, int* __restrict__ deg,
                                 int E, int N) {
  int e = blockIdx.x * 256 + threadIdx.x;
  int EP = E + N;
  if (e < EP) {
    int d = (e < E) ? ei[E + e] : (e - E);   // self-loop tail
    atomicAdd(&deg[d], 1);
  }
}

__global__ void scan_block_kernel(const int* __restrict__ deg, int* __restrict__ rowp,
                                  int* __restrict__ partials, int N) {
  __shared__ int sm[1024];
  int t = threadIdx.x;
  int i = blockIdx.x * 1024 + t;
  int v = (i < N) ? deg[i] : 0;
  sm[t] = v;
  __syncthreads();
  for (int off = 1; off < 1024; off <<= 1) {
    int tmp = (t >= off) ? sm[t - off] : 0;
    __syncthreads();
    sm[t] += tmp;
    __syncthreads();
  }
  if (i < N) rowp[i] = sm[t] - v;            // exclusive within block
  if (t == 1023) partials[blockIdx.x] = sm[t];
}

// single 1024-thr block LDS scan (nb <= 1024); replaces 1-thread serial loop
__global__ void scan_partials_kernel(int* partials, int nb) {
  __shared__ int sm[1024];
  int t = threadIdx.x;
  int v = (t < nb) ? partials[t] : 0;
  sm[t] = v;
  __syncthreads();
  for (int off = 1; off < 1024; off <<= 1) {
    int tmp = (t >= off) ? sm[t - off] : 0;
    __syncthreads();
    sm[t] += tmp;
    __syncthreads();
  }
  if (t < nb) partials[t] = sm[t] - v;       // exclusive
}

__global__ void add_off_kernel(int* __restrict__ rowp, const int* __restrict__ partials,
                               int N, int EP) {
  int i = blockIdx.x * 256 + threadIdx.x;
  if (i < N) rowp[i] += partials[i >> 10];
  if (i == 0) rowp[N] = EP;
}

__global__ void scatter_kernel(const int* __restrict__ ei, const int* __restrict__ rowp,
                               int* __restrict__ cursor, int* __restrict__ col,
                               int* __restrict__ dstarr, int E, int N) {
  int e = blockIdx.x * 256 + threadIdx.x;
  int EP = E + N;
  if (e < EP) {
    int s, d;
    if (e < E) { s = ei[e]; d = ei[E + e]; }
    else       { s = e - E; d = e - E; }
    int pos = rowp[d] + atomicAdd(&cursor[d], 1);
    col[pos] = s;
    dstarr[pos] = d;
  }
}

// ---------------- fp32 -> fp16 conversions ----------------

__global__ void convert_x_kernel(const float* __restrict__ X, _Float16* __restrict__ Xh,
                                 int total8) {
  int i = blockIdx.x * 256 + threadIdx.x;
  if (i < total8) {
    float4 a = *(const float4*)&X[i * 8];
    float4 b = *(const float4*)&X[i * 8 + 4];
    half8 o = { (_Float16)a.x, (_Float16)a.y, (_Float16)a.z, (_Float16)a.w,
                (_Float16)b.x, (_Float16)b.y, (_Float16)b.z, (_Float16)b.w };
    *(half8*)&Xh[i * 8] = o;
  }
}

// all three W [128,Fout] fp32 -> Wt [Fout,128] fp16, one launch (blockIdx.y selects)
__global__ void convert_wt3_kernel(const float* __restrict__ W1, _Float16* __restrict__ Wt1,
                                   const float* __restrict__ W2, _Float16* __restrict__ Wt2,
                                   const float* __restrict__ W3, _Float16* __restrict__ Wt3) {
  const float* W; _Float16* Wt; int Fout;
  if (blockIdx.y == 0)      { W = W1; Wt = Wt1; Fout = 128; }
  else if (blockIdx.y == 1) { W = W2; Wt = Wt2; Fout = 128; }
  else                      { W = W3; Wt = Wt3; Fout = 256; }
  int i = blockIdx.x * 256 + threadIdx.x;
  if (i < 128 * Fout) {
    int c = i >> 7, k = i & 127;
    Wt[c * 128 + k] = (_Float16)W[k * Fout + c];
  }
}

// ---------------- MFMA GEMM: Xh [N,128] f16 @ Wt [Fout,128] f16 -> O [N,Fout] f16 ----

__global__ __launch_bounds__(256) void gemm_mfma_kernel(
    const _Float16* __restrict__ X, const _Float16* __restrict__ Wt,
    _Float16* __restrict__ O, int N, int Fout) {
  const int w = threadIdx.x >> 6;
  const int lane = threadIdx.x & 63;
  const int r = lane & 15, g = lane >> 4;
  const int row0 = blockIdx.x * 64 + w * 16;
  const int colpan = blockIdx.y * 128;

  int rowl = row0 + r;
  if (rowl >= N) rowl = N - 1;                     // clamp for loads; store guarded

  f32x4 acc[8];
#pragma unroll
  for (int c = 0; c < 8; ++c) acc[c] = {0.f, 0.f, 0.f, 0.f};

#pragma unroll
  for (int s = 0; s < 4; ++s) {
    half8 a = *(const half8*)&X[(size_t)rowl * 128 + s * 32 + g * 8];
#pragma unroll
    for (int c = 0; c < 8; ++c) {
      half8 b = *(const half8*)&Wt[(size_t)(colpan + c * 16 + r) * 128 + s * 32 + g * 8];
      acc[c] = __builtin_amdgcn_mfma_f32_16x16x32_f16(a, b, acc[c], 0, 0, 0);
    }
  }

#pragma unroll
  for (int c = 0; c < 8; ++c) {
    int ocol = colpan + c * 16 + r;
#pragma unroll
    for (int q = 0; q < 4; ++q) {
      int orow = row0 + g * 4 + q;
      if (orow < N) O[(size_t)orow * Fout + ocol] = (_Float16)acc[c][q];
    }
  }
}

// ---------------- per-node attention logits, vectorized ----------------
// LP lanes per (node,head) pair, each loads half8; pair = n*4+h so H access is
// fully coalesced (flat = pair*C + sub*8). Reduce across LP lanes via shfl_xor.

template <int LP>
__global__ __launch_bounds__(256) void alpha_kernel(
    const _Float16* __restrict__ H, const float* __restrict__ a_s,
    const float* __restrict__ a_d, float* __restrict__ asrc,
    float* __restrict__ adst, int N) {
  const int C = LP * 8;
  int g = blockIdx.x * 256 + threadIdx.x;
  int pair = g / LP;                 // n*4 + h
  int sub = g % LP;
  if (pair >= N * 4) return;
  int h = pair & 3;
  half8 hv = *(const half8*)&H[(size_t)pair * C + sub * 8];
  float4 s0 = *(const float4*)&a_s[h * C + sub * 8];
  float4 s1 = *(const float4*)&a_s[h * C + sub * 8 + 4];
  float4 d0 = *(const float4*)&a_d[h * C + sub * 8];
  float4 d1 = *(const float4*)&a_d[h * C + sub * 8 + 4];
  float ps = (float)hv[0] * s0.x + (float)hv[1] * s0.y + (float)hv[2] * s0.z +
             (float)hv[3] * s0.w + (float)hv[4] * s1.x + (float)hv[5] * s1.y +
             (float)hv[6] * s1.z + (float)hv[7] * s1.w;
  float pd = (float)hv[0] * d0.x + (float)hv[1] * d0.y + (float)hv[2] * d0.z +
             (float)hv[3] * d0.w + (float)hv[4] * d1.x + (float)hv[5] * d1.y +
             (float)hv[6] * d1.z + (float)hv[7] * d1.w;
#pragma unroll
  for (int off = 1; off < LP; off <<= 1) {
    ps += __shfl_xor(ps, off, 64);
    pd += __shfl_xor(pd, off, 64);
  }
  if (sub == 0) { asrc[pair] = ps; adst[pair] = pd; }
}

// ---------------- per-edge softmax weights (once per (edge,head)) ----------------

__global__ __launch_bounds__(256) void ew_kernel(
    const int* __restrict__ col, const int* __restrict__ dstarr,
    const float* __restrict__ asrc, const float* __restrict__ adst,
    float* __restrict__ wgt, int EP) {
  int j = blockIdx.x * 256 + threadIdx.x;
  if (j < EP) {
    int s = col[j], d = dstarr[j];
    float4 a = *(const float4*)&asrc[s * 4];
    float4 b = *(const float4*)&adst[d * 4];
    float4 o;
    o.x = __expf(lrelu(a.x + b.x));
    o.y = __expf(lrelu(a.y + b.y));
    o.z = __expf(lrelu(a.z + b.z));
    o.w = __expf(lrelu(a.w + b.w));
    *(float4*)&wgt[j * 4] = o;
  }
}

// ---------------- atomic-free aggregation (weights preloaded, unroll-4) ----------------
// 4 waves per block = 4 nodes; lane handles one half2 (2 of 128 ch).

__global__ __launch_bounds__(256) void aggregate_concat_kernel(
    const _Float16* __restrict__ H, const float* __restrict__ wgt,
    const float* __restrict__ bias, const int* __restrict__ rowp,
    const int* __restrict__ col, _Float16* __restrict__ out, int N) {
  int n = blockIdx.x * 4 + (threadIdx.x >> 6);
  if (n >= N) return;
  int lane = threadIdx.x & 63;     // channels 2*lane, 2*lane+1
  int h = lane >> 4;               // 16 lanes per head (32 ch)
  int j = rowp[n], end = rowp[n + 1];
  float ax = 0.f, ay = 0.f, denom = 0.f;
  for (; j + 3 < end; j += 4) {
    int s0 = col[j], s1 = col[j + 1], s2 = col[j + 2], s3 = col[j + 3];
    float w0 = wgt[j * 4 + h];
    float w1 = wgt[j * 4 + 4 + h];
    float w2 = wgt[j * 4 + 8 + h];
    float w3 = wgt[j * 4 + 12 + h];
    half2v f0 = *(const half2v*)&H[s0 * 128 + lane * 2];
    half2v f1 = *(const half2v*)&H[s1 * 128 + lane * 2];
    half2v f2 = *(const half2v*)&H[s2 * 128 + lane * 2];
    half2v f3 = *(const half2v*)&H[s3 * 128 + lane * 2];
    denom += (w0 + w1) + (w2 + w3);
    ax += w0 * (float)f0.x + w1 * (float)f1.x + w2 * (float)f2.x + w3 * (float)f3.x;
    ay += w0 * (float)f0.y + w1 * (float)f1.y + w2 * (float)f2.y + w3 * (float)f3.y;
  }
  for (; j < end; ++j) {
    int s0 = col[j];
    float w0 = wgt[j * 4 + h];
    half2v f0 = *(const half2v*)&H[s0 * 128 + lane * 2];
    denom += w0;
    ax += w0 * (float)f0.x;
    ay += w0 * (float)f0.y;
  }
  float inv = 1.f / denom;
  half2v o;
  o.x = (_Float16)(ax * inv + bias[lane * 2]);
  o.y = (_Float16)(ay * inv + bias[lane * 2 + 1]);
  *(half2v*)&out[n * 128 + lane * 2] = o;
}

// layer 3: H rows 256 ch fp16; 128 thr/node; mean over 4 heads -> 64 ch fp32 out.

__global__ __launch_bounds__(128) void aggregate_mean_kernel(
    const _Float16* __restrict__ H, const float* __restrict__ wgt,
    const float* __restrict__ bias, const int* __restrict__ rowp,
    const int* __restrict__ col, float* __restrict__ out, int N) {
  __shared__ float2 red[128];
  int n = blockIdx.x;
  int t = threadIdx.x;             // channels 2t, 2t+1
  int h = t >> 5;                  // 32 threads per head (64 ch)
  int j = rowp[n], end = rowp[n + 1];
  float ax = 0.f, ay = 0.f, denom = 0.f;
  for (; j + 3 < end; j += 4) {
    int s0 = col[j], s1 = col[j + 1], s2 = col[j + 2], s3 = col[j + 3];
    float w0 = wgt[j * 4 + h];
    float w1 = wgt[j * 4 + 4 + h];
    float w2 = wgt[j * 4 + 8 + h];
    float w3 = wgt[j * 4 + 12 + h];
    half2v f0 = *(const half2v*)&H[s0 * 256 + t * 2];
    half2v f1 = *(const half2v*)&H[s1 * 256 + t * 2];
    half2v f2 = *(const half2v*)&H[s2 * 256 + t * 2];
    half2v f3 = *(const half2v*)&H[s3 * 256 + t * 2];
    denom += (w0 + w1) + (w2 + w3);
    ax += w0 * (float)f0.x + w1 * (float)f1.x + w2 * (float)f2.x + w3 * (float)f3.x;
    ay += w0 * (float)f0.y + w1 * (float)f1.y + w2 * (float)f2.y + w3 * (float)f3.y;
  }
  for (; j < end; ++j) {
    int s0 = col[j];
    float w0 = wgt[j * 4 + h];
    half2v f0 = *(const half2v*)&H[s0 * 256 + t * 2];
    denom += w0;
    ax += w0 * (float)f0.x;
    ay += w0 * (float)f0.y;
  }
  float inv = 1.f / denom;
  red[t] = make_float2(ax * inv, ay * inv);
  __syncthreads();
  if (t < 32) {
    float2 r0 = red[t], r1 = red[t + 32], r2 = red[t + 64], r3 = red[t + 96];
    float2 o = make_float2(0.25f * (r0.x + r1.x + r2.x + r3.x) + bias[t * 2],
                           0.25f * (r0.y + r1.y + r2.y + r3.y) + bias[t * 2 + 1]);
    *(float2*)&out[n * 64 + t * 2] = o;
  }
}

// ---------------- host launch ----------------

extern "C" void kernel_launch(void* const* d_in, const int* in_sizes, int n_in,
                              void* d_out, int out_size, void* d_ws, size_t ws_size,
                              hipStream_t stream) {
  const float* x   = (const float*)d_in[0];
  const int*   ei  = (const int*)d_in[1];
  const float* W1  = (const float*)d_in[2];
  const float* as1 = (const float*)d_in[3];
  const float* ad1 = (const float*)d_in[4];
  const float* b1  = (const float*)d_in[5];
  const float* W2  = (const float*)d_in[6];
  const float* as2 = (const float*)d_in[7];
  const float* ad2 = (const float*)d_in[8];
  const float* b2  = (const float*)d_in[9];
  const float* W3  = (const float*)d_in[10];
  const float* as3 = (const float*)d_in[11];
  const float* ad3 = (const float*)d_in[12];
  const float* b3  = (const float*)d_in[13];
  float* out = (float*)d_out;

  const int N  = in_sizes[0] / 128;
  const int E  = in_sizes[1] / 2;
  const int EP = E + N;

  char* p = (char*)d_ws;
  auto carve = [&](size_t bytes) -> void* {
    void* r = (void*)p;
    p += (bytes + 255) & ~size_t(255);
    return r;
  };
  int*      deg  = (int*)carve(size_t(N) * 4);
  int*      rowp = (int*)carve(size_t(N + 1) * 4);
  int*      cur  = (int*)carve(size_t(N) * 4);
  int*      part = (int*)carve(1024 * 4);
  int*      col  = (int*)carve(size_t(EP) * 4);
  int*      darr = (int*)carve(size_t(EP) * 4);
  float*    asrc = (float*)carve(size_t(N) * HEADS * 4);
  float*    adst = (float*)carve(size_t(N) * HEADS * 4);
  float*    wgt  = (float*)carve(size_t(EP) * HEADS * 4);
  _Float16* Xh   = (_Float16*)carve(size_t(N) * 128 * 2);
  _Float16* Wt1  = (_Float16*)carve(128 * 128 * 2);
  _Float16* Wt2  = (_Float16*)carve(128 * 128 * 2);
  _Float16* Wt3  = (_Float16*)carve(256 * 128 * 2);
  _Float16* Hb   = (_Float16*)carve(size_t(N) * 256 * 2);  // gemm outputs
  _Float16* Ab   = (_Float16*)carve(size_t(N) * 128 * 2);  // aggregation outputs

  hipMemsetAsync(deg, 0, size_t(N) * 4, stream);
  hipMemsetAsync(cur, 0, size_t(N) * 4, stream);

  int gEP = (EP + 255) / 256;
  count_deg_kernel<<<gEP, 256, 0, stream>>>(ei, deg, E, N);
  int nb = (N + 1023) / 1024;
  scan_block_kernel<<<nb, 1024, 0, stream>>>(deg, rowp, part, N);
  scan_partials_kernel<<<1, 1024, 0, stream>>>(part, nb);
  add_off_kernel<<<(N + 256) / 256, 256, 0, stream>>>(rowp, part, N, EP);
  scatter_kernel<<<gEP, 256, 0, stream>>>(ei, rowp, cur, col, darr, E, N);

  convert_x_kernel<<<(N * 128 / 8 + 255) / 256, 256, 0, stream>>>(x, Xh, N * 128 / 8);
  convert_wt3_kernel<<<dim3(128, 3), 256, 0, stream>>>(W1, Wt1, W2, Wt2, W3, Wt3);

  int gM = (N + 63) / 64;
  int gN4 = (N + 3) / 4;
  int gA32 = (N * 4 * 4 + 255) / 256;   // alpha LP=4 (C=32)
  int gA64 = (N * 4 * 8 + 255) / 256;   // alpha LP=8 (C=64)

  // layer 1
  gemm_mfma_kernel<<<dim3(gM, 1), 256, 0, stream>>>(Xh, Wt1, Hb, N, 128);
  alpha_kernel<4><<<gA32, 256, 0, stream>>>(Hb, as1, ad1, asrc, adst, N);
  ew_kernel<<<gEP, 256, 0, stream>>>(col, darr, asrc, adst, wgt, EP);
  aggregate_concat_kernel<<<gN4, 256, 0, stream>>>(Hb, wgt, b1, rowp, col, Ab, N);
  // layer 2
  gemm_mfma_kernel<<<dim3(gM, 1), 256, 0, stream>>>(Ab, Wt2, Hb, N, 128);
  alpha_kernel<4><<<gA32, 256, 0, stream>>>(Hb, as2, ad2, asrc, adst, N);
  ew_kernel<<<gEP, 256, 0, stream>>>(col, darr, asrc, adst, wgt, EP);
  aggregate_concat_kernel<<<gN4, 256, 0, stream>>>(Hb, wgt, b2, rowp, col, Ab, N);
  // layer 3 (Fout=256, mean over heads)
  gemm_mfma_kernel<<<dim3(gM, 2), 256, 0, stream>>>(Ab, Wt3, Hb, N, 256);
  alpha_kernel<8><<<gA64, 256, 0, stream>>>(Hb, as3, ad3, asrc, adst, N);
  ew_kernel<<<gEP, 256, 0, stream>>>(col, darr, asrc, adst, wgt, EP);
  aggregate_mean_kernel<<<N, 128, 0, stream>>>(Hb, wgt, b3, rowp, col, out, N);
}